// Round 24
// baseline (61.744 us; speedup 1.0000x reference)
//
#include <hip/hip_runtime.h>
#include <hip/hip_bf16.h>
#include <stdint.h>

#define N_ROWS 16384
#define O_ROWS 1024
#define K_DIM  512

typedef __bf16 bf16x8 __attribute__((ext_vector_type(8)));
typedef float  f32x4  __attribute__((ext_vector_type(4)));

__device__ __forceinline__ ushort f2bfu(float f) {
    __bf16 h = (__bf16)f;
    return __builtin_bit_cast(ushort, h);
}

#define BAR_LGKM()  do {                                        \
    asm volatile("s_waitcnt lgkmcnt(0)" ::: "memory");          \
    __builtin_amdgcn_s_barrier();                               \
} while (0)

// ---------------------------------------------------------------------------
// Round 24: PRODUCER/CONSUMER WAVE SPECIALIZATION (plain-HIP AITER pattern).
// Diagnosis across r12-r23: HBM (100MB -> 16us) flows only during staging
// phases (~45% duty) -> 35us wall contribution = the observed plateau.
// Fix: waves 0-3 = producers (load+sumsq+cvt+ds_write, continuous HBM),
// waves 4-7 = consumers (ds_read+MFMA only). Dbuf LDS (96KB), ONE lgkm
// barrier/kt: producers stage kt+1 -> buf[kt+1&1] while consumers MFMA kt
// from buf[kt&1] (disjoint). HBM duty -> ~100%.
//  - 256x128 tile, BK=64; consumers 2x2 grid of 128x64 tiles, acc 8x4.
//  - T2 XOR-swizzle, bijective XCD swizzle, extended-K-tile epilogue
//    (producers write it, consumers consume), #pragma unroll 1.
//  - no barrier after producers' last one (exited-wave safety).
// ---------------------------------------------------------------------------
__global__ __launch_bounds__(512) void quadra_kernel(
    const float* __restrict__ x, const float* __restrict__ mean,
    float* __restrict__ out)
{
    __shared__ ushort sA[2][256 * 64];   // 64 KiB (swizzled bf16 x)
    __shared__ ushort sB[2][128 * 64];   // 32 KiB (swizzled bf16 -2*mean)

    const int bid  = blockIdx.x;                // 0..511
    const int t    = (bid & 7) * 64 + (bid >> 3);
    const int brow = (t >> 3) * 256;
    const int bcol = (t & 7) * 128;

    const int tid  = threadIdx.x;
    const int lane = tid & 63;
    const int wid  = tid >> 6;                  // 0..7
    const int cl = lane & 15, hi = lane >> 4;
    const bool producer = (wid < 4);

    // ---- producer geometry (tid 0..255) ----
    // A: r0 = tid>>3 (0..31), q = tid&7; rows r0+32i (i=0..7), k-octet q*8.
    // B: rb = tid>>2 (0..63), qb = tid&3; rows rb+64i (i=0..1), k = qb*16.
    const int r0 = (tid >> 3) & 31;
    const int q  = tid & 7;
    const int rb = (tid >> 2) & 63;
    const int qb = tid & 3;
    const float* gA = x    + (size_t)(brow + r0) * K_DIM + q * 8;
    const float* gB = mean + (size_t)(bcol + rb) * K_DIM + qb * 16;

    // ---- consumer geometry (waves 4..7) ----
    const int cw = wid - 4;                     // 0..3
    const int cr = (cw >> 1) & 1, cc = cw & 1;  // 2x2 grid of 128x64 tiles

    f32x4 acc[8][4] = {};
    float asq[8] = {0,0,0,0,0,0,0,0};
    float bsq[2] = {0.f, 0.f};

    // ================= producer staging macro-body =================
    #define STAGE(KT, BUF) do {                                              \
        ushort* dA = &sA[BUF][0];                                            \
        ushort* dB = &sB[BUF][0];                                            \
        _Pragma("unroll")                                                    \
        for (int i = 0; i < 8; ++i) {                                        \
            const float* p = gA + (size_t)(i * 32) * K_DIM + (KT) * 64;      \
            f32x4 v0 = *(const f32x4*)(p);                                   \
            f32x4 v1 = *(const f32x4*)(p + 4);                               \
            asq[i] += v0[0]*v0[0] + v0[1]*v0[1] + v0[2]*v0[2] + v0[3]*v0[3]  \
                    + v1[0]*v1[0] + v1[1]*v1[1] + v1[2]*v1[2] + v1[3]*v1[3]; \
            bf16x8 cv;                                                       \
            cv[0] = (__bf16)v0[0]; cv[1] = (__bf16)v0[1];                    \
            cv[2] = (__bf16)v0[2]; cv[3] = (__bf16)v0[3];                    \
            cv[4] = (__bf16)v1[0]; cv[5] = (__bf16)v1[1];                    \
            cv[6] = (__bf16)v1[2]; cv[7] = (__bf16)v1[3];                    \
            const int row = r0 + i * 32;                                     \
            const int wb  = (q * 16) ^ ((row & 7) << 4);                     \
            *(bf16x8*)(dA + row * 64 + (wb >> 1)) = cv;                      \
        }                                                                    \
        _Pragma("unroll")                                                    \
        for (int i = 0; i < 2; ++i) {                                        \
            const float* p = gB + (size_t)(i * 64) * K_DIM + (KT) * 64;      \
            f32x4 v0 = *(const f32x4*)(p);                                   \
            f32x4 v1 = *(const f32x4*)(p + 4);                               \
            f32x4 v2 = *(const f32x4*)(p + 8);                               \
            f32x4 v3 = *(const f32x4*)(p + 12);                              \
            bsq[i] += v0[0]*v0[0] + v0[1]*v0[1] + v0[2]*v0[2] + v0[3]*v0[3]  \
                    + v1[0]*v1[0] + v1[1]*v1[1] + v1[2]*v1[2] + v1[3]*v1[3]  \
                    + v2[0]*v2[0] + v2[1]*v2[1] + v2[2]*v2[2] + v2[3]*v2[3]  \
                    + v3[0]*v3[0] + v3[1]*v3[1] + v3[2]*v3[2] + v3[3]*v3[3]; \
            bf16x8 c0, c1;                                                   \
            c0[0] = (__bf16)(v0[0] * -2.0f); c0[1] = (__bf16)(v0[1] * -2.0f);\
            c0[2] = (__bf16)(v0[2] * -2.0f); c0[3] = (__bf16)(v0[3] * -2.0f);\
            c0[4] = (__bf16)(v1[0] * -2.0f); c0[5] = (__bf16)(v1[1] * -2.0f);\
            c0[6] = (__bf16)(v1[2] * -2.0f); c0[7] = (__bf16)(v1[3] * -2.0f);\
            c1[0] = (__bf16)(v2[0] * -2.0f); c1[1] = (__bf16)(v2[1] * -2.0f);\
            c1[2] = (__bf16)(v2[2] * -2.0f); c1[3] = (__bf16)(v2[3] * -2.0f);\
            c1[4] = (__bf16)(v3[0] * -2.0f); c1[5] = (__bf16)(v3[1] * -2.0f);\
            c1[6] = (__bf16)(v3[2] * -2.0f); c1[7] = (__bf16)(v3[3] * -2.0f);\
            const int row = rb + i * 64;                                     \
            const int swz = (row & 7) << 4;                                  \
            *(bf16x8*)(dB + row * 64 + (((qb * 32)      ^ swz) >> 1)) = c0;  \
            *(bf16x8*)(dB + row * 64 + (((qb * 32 + 16) ^ swz) >> 1)) = c1;  \
        }                                                                    \
    } while (0)

    // prologue: stage kt=0 into buf 0
    if (producer) STAGE(0, 0);
    BAR_LGKM();

    #pragma unroll 1
    for (int kt = 0; kt < 8; ++kt) {
        if (producer) {
            if (kt < 7) {
                const int nb = (kt + 1) & 1;
                if (nb) STAGE(kt + 1, 1); else STAGE(kt + 1, 0);
            }
        } else {
            const ushort* bufA = &sA[kt & 1][0];
            const ushort* bufB = &sB[kt & 1][0];
            #pragma unroll
            for (int ks = 0; ks < 2; ++ks) {
                bf16x8 a[8], b[4];
                #pragma unroll
                for (int m = 0; m < 8; ++m) {
                    const int row = cr*128 + m*16 + cl;
                    const int rbo = (ks*64 + hi*16) ^ ((row & 7) << 4);
                    a[m] = *(const bf16x8*)(bufA + row * 64 + (rbo >> 1));
                }
                #pragma unroll
                for (int n = 0; n < 4; ++n) {
                    const int row = cc*64 + n*16 + cl;
                    const int rbo = (ks*64 + hi*16) ^ ((row & 7) << 4);
                    b[n] = *(const bf16x8*)(bufB + row * 64 + (rbo >> 1));
                }
                #pragma unroll
                for (int m = 0; m < 8; ++m)
                    #pragma unroll
                    for (int n = 0; n < 4; ++n)
                        acc[m][n] = __builtin_amdgcn_mfma_f32_16x16x32_bf16(
                            a[m], b[n], acc[m][n], 0, 0, 0);
            }
        }
        BAR_LGKM();
    }

    // ---- extended K-tile: producers write, consumers consume ----
    //   sAe[row(256)] = [xsq, 1, 0 x30]   sBe[row(128)] = [1, msq, 0 x30]
    ushort* sAe = &sA[0][0];    // 16 KB
    ushort* sBe = &sB[0][0];    //  8 KB
    if (producer) {
        #pragma unroll
        for (int i = 0; i < 8; ++i) {
            float sa = asq[i];
            sa += __shfl_xor(sa, 1);
            sa += __shfl_xor(sa, 2);
            sa += __shfl_xor(sa, 4);
            const int row = r0 + i * 32;
            uint2 aw = {0u, 0u};
            if (q == 0) aw.x = (uint32_t)f2bfu(sa) | (0x3F80u << 16); // [xsq,1]
            *(uint2*)(sAe + row * 32 + q * 4) = aw;
        }
        #pragma unroll
        for (int i = 0; i < 2; ++i) {
            float sb = bsq[i];
            sb += __shfl_xor(sb, 1);
            sb += __shfl_xor(sb, 2);
            const int row = rb + i * 64;
            uint4 bw = {0u, 0u, 0u, 0u};
            if (qb == 0) bw.x = 0x3F80u | ((uint32_t)f2bfu(sb) << 16); // [1,msq]
            *(uint4*)(sBe + row * 32 + qb * 8) = bw;
        }
    }
    BAR_LGKM();   // last barrier; producers do nothing after this

    if (!producer) {
        {   // extra MFMA: adds xsq[r] + msq[o] into every accumulator element
            bf16x8 a[8], b[4];
            #pragma unroll
            for (int m = 0; m < 8; ++m)
                a[m] = *(const bf16x8*)(sAe + (cr*128 + m*16 + cl) * 32 + hi * 8);
            #pragma unroll
            for (int n = 0; n < 4; ++n)
                b[n] = *(const bf16x8*)(sBe + (cc*64 + n*16 + cl) * 32 + hi * 8);
            #pragma unroll
            for (int m = 0; m < 8; ++m)
                #pragma unroll
                for (int n = 0; n < 4; ++n)
                    acc[m][n] = __builtin_amdgcn_mfma_f32_16x16x32_bf16(
                        a[m], b[n], acc[m][n], 0, 0, 0);
        }

        // epilogue: C/D layout col = lane&15, row = (lane>>4)*4 + j
        #pragma unroll
        for (int m = 0; m < 8; ++m) {
            #pragma unroll
            for (int j = 0; j < 4; ++j) {
                const int grow = brow + cr*128 + m*16 + hi*4 + j;
                float* orow = out + (size_t)grow * O_ROWS + bcol + cc*64 + cl;
                #pragma unroll
                for (int n = 0; n < 4; ++n)
                    orow[n * 16] = rsqrtf(acc[m][n][j]);
            }
        }
    }
    #undef STAGE
}

extern "C" void kernel_launch(void* const* d_in, const int* in_sizes, int n_in,
                              void* d_out, int out_size, void* d_ws, size_t ws_size,
                              hipStream_t stream) {
    const float* x    = (const float*)d_in[0];
    const float* mean = (const float*)d_in[1];
    float* out = (float*)d_out;

    quadra_kernel<<<dim3((N_ROWS / 256) * (O_ROWS / 128)), 512, 0, stream>>>(
        x, mean, out);
}

// Round 25
// 48.792 us; speedup vs baseline: 1.2655x; 1.2655x over previous
//
#include <hip/hip_runtime.h>
#include <hip/hip_bf16.h>
#include <stdint.h>

#define N_ROWS 16384
#define O_ROWS 1024
#define K_DIM  512

typedef __bf16 bf16x8 __attribute__((ext_vector_type(8)));
typedef float  f32x4  __attribute__((ext_vector_type(4)));

__device__ __forceinline__ ushort f2bfu(float f) {
    __bf16 h = (__bf16)f;
    return __builtin_bit_cast(ushort, h);
}

#define BAR_LGKM()  do {                                        \
    asm volatile("s_waitcnt lgkmcnt(0)" ::: "memory");          \
    __builtin_amdgcn_s_barrier();                               \
} while (0)

// ---------------------------------------------------------------------------
// Round 25: combine the two PROVEN levers -- intra-kt interleave (+9%, r21)
// and 2 blocks/CU (+17%, r16) -- via BK=32 full double-buffer (48 KB).
// r22's failure was its 8B write units covering only half the bank groups
// (4-way conflict, 1.7M). Fixed: threads write 16B units spanning the FULL
// packed 128B row (u2 = tid&7 over both pair-halves) -> exactly r16's
// verified conflict-free write pattern.
//  - 256x128 tile, 16 kt of K=32; LDS rows = packed row-pairs (logical rows
//    r and r+128 share a 128B row; lr = r&127, byte += (r>>7)*64), XOR
//    swizzle ^((lr&7)<<4) on writes and reads.
//  - per kt: {issue 6 loads(kt+1) -> ds_read a4/b4 -> 8 MFMA ->
//             cvt+sumsq+3x ds_write(kt+1)->nxt -> 8 MFMA -> BAR(lgkm)}
//  - 512 thr, 8 waves (4x2), 64x64 wave tiles, acc 4x4 = 64 AGPR.
//  - bijective XCD swizzle, extended-K-tile epilogue, #pragma unroll 1.
// ---------------------------------------------------------------------------
__global__ __launch_bounds__(512) void quadra_kernel(
    const float* __restrict__ x, const float* __restrict__ mean,
    float* __restrict__ out)
{
    __shared__ ushort sA[2][128 * 64];   // A: 256 rows pair-packed, 16 KiB/buf
    __shared__ ushort sB[2][64 * 64];    // B: 128 rows pair-packed, 8 KiB/buf

    const int bid  = blockIdx.x;                // 0..511
    const int t    = (bid & 7) * 64 + (bid >> 3);
    const int brow = (t >> 3) * 256;
    const int bcol = (t & 7) * 128;

    const int tid  = threadIdx.x;
    const int lane = tid & 63;
    const int wid  = tid >> 6;                  // 0..7
    const int wr = wid >> 1, wc = wid & 1;      // 4x2 wave grid, 64x64 out each
    const int cl = lane & 15, hi = lane >> 4;

    f32x4 acc[4][4] = {};

    // staging geometry: sr = tid>>3 (0..63) = packed LDS row; u2 = tid&7 is
    // the 16B unit within the 128B packed row; upair = u2>>2 selects the
    // logical-row half (+128 for A, +64 for B); uk = u2&3 is the k-octet.
    const int sr    = tid >> 3;
    const int u2    = tid & 7;
    const int upair = u2 >> 2;
    const int uk    = u2 & 3;

    // A logical rows: sr + i*64 + upair*128 (i=0,1); k = kt*32 + uk*8
    const float* gA = x + (size_t)(brow + sr + upair * 128) * K_DIM + uk * 8;
    // B logical row: sr + upair*64; k = kt*32 + uk*8
    const float* gB = mean + (size_t)(bcol + sr + upair * 64) * K_DIM + uk * 8;

    // constant LDS write offsets (ushort units)
    const int swzA = (sr & 7) << 4;
    const int offA0 = (sr)      * 64 + (((u2 * 16) ^ swzA) >> 1);
    const int offA1 = (sr + 64) * 64 + (((u2 * 16) ^ swzA) >> 1);
    const int offB  = (sr)      * 64 + (((u2 * 16) ^ swzA) >> 1);

    float asq[2] = {0.f, 0.f};
    float bsq = 0.f;

    f32x4 pa[2][2], pb[2];

    #define LOADK(KT) do {                                                   \
        pa[0][0] = *(const f32x4*)(gA + (KT) * 32);                          \
        pa[0][1] = *(const f32x4*)(gA + (KT) * 32 + 4);                      \
        pa[1][0] = *(const f32x4*)(gA + (size_t)64 * K_DIM + (KT) * 32);     \
        pa[1][1] = *(const f32x4*)(gA + (size_t)64 * K_DIM + (KT) * 32 + 4); \
        pb[0]    = *(const f32x4*)(gB + (KT) * 32);                          \
        pb[1]    = *(const f32x4*)(gB + (KT) * 32 + 4);                      \
    } while (0)

    #define STAGEK(BUF) do {                                                 \
        _Pragma("unroll")                                                    \
        for (int i = 0; i < 2; ++i) {                                        \
            f32x4 v0 = pa[i][0], v1 = pa[i][1];                              \
            asq[i] += v0[0]*v0[0] + v0[1]*v0[1] + v0[2]*v0[2] + v0[3]*v0[3]  \
                    + v1[0]*v1[0] + v1[1]*v1[1] + v1[2]*v1[2] + v1[3]*v1[3]; \
            bf16x8 cv;                                                       \
            cv[0] = (__bf16)v0[0]; cv[1] = (__bf16)v0[1];                    \
            cv[2] = (__bf16)v0[2]; cv[3] = (__bf16)v0[3];                    \
            cv[4] = (__bf16)v1[0]; cv[5] = (__bf16)v1[1];                    \
            cv[6] = (__bf16)v1[2]; cv[7] = (__bf16)v1[3];                    \
            *(bf16x8*)(&sA[BUF][0] + (i ? offA1 : offA0)) = cv;              \
        }                                                                    \
        {                                                                    \
            f32x4 v0 = pb[0], v1 = pb[1];                                    \
            bsq += v0[0]*v0[0] + v0[1]*v0[1] + v0[2]*v0[2] + v0[3]*v0[3]     \
                 + v1[0]*v1[0] + v1[1]*v1[1] + v1[2]*v1[2] + v1[3]*v1[3];    \
            bf16x8 cv;                                                       \
            cv[0] = (__bf16)(v0[0] * -2.0f); cv[1] = (__bf16)(v0[1] * -2.0f);\
            cv[2] = (__bf16)(v0[2] * -2.0f); cv[3] = (__bf16)(v0[3] * -2.0f);\
            cv[4] = (__bf16)(v1[0] * -2.0f); cv[5] = (__bf16)(v1[1] * -2.0f);\
            cv[6] = (__bf16)(v1[2] * -2.0f); cv[7] = (__bf16)(v1[3] * -2.0f);\
            *(bf16x8*)(&sB[BUF][0] + offB) = cv;                             \
        }                                                                    \
    } while (0)

    // prologue: stage kt=0 into buf 0
    LOADK(0);
    STAGEK(0);
    BAR_LGKM();

    #pragma unroll 1
    for (int kt = 0; kt < 16; ++kt) {
        const int cur = kt & 1;

        // issue loads for kt+1 (fly under the first MFMA half)
        if (kt < 15) LOADK(kt + 1);

        // ds_read fragments from buf[cur] (K=32: one mfma per m,n)
        bf16x8 a[4], b[4];
        #pragma unroll
        for (int m = 0; m < 4; ++m) {
            const int row = wr*64 + m*16 + cl;
            const int lr  = row & 127;
            const int by  = ((row >> 7) * 64 + hi * 16) ^ ((lr & 7) << 4);
            a[m] = *(const bf16x8*)(&sA[cur][0] + lr * 64 + (by >> 1));
        }
        #pragma unroll
        for (int n = 0; n < 4; ++n) {
            const int row = wc*64 + n*16 + cl;
            const int lr  = row & 63;
            const int by  = ((row >> 6) * 64 + hi * 16) ^ ((lr & 7) << 4);
            b[n] = *(const bf16x8*)(&sB[cur][0] + lr * 64 + (by >> 1));
        }

        // first MFMA half (m = 0,1)
        #pragma unroll
        for (int m = 0; m < 2; ++m)
            #pragma unroll
            for (int n = 0; n < 4; ++n)
                acc[m][n] = __builtin_amdgcn_mfma_f32_16x16x32_bf16(
                    a[m], b[n], acc[m][n], 0, 0, 0);

        // stage kt+1 into the other buffer (hides under MFMA)
        if (kt < 15) {
            if (cur) STAGEK(0); else STAGEK(1);
        }

        // second MFMA half (m = 2,3)
        #pragma unroll
        for (int m = 2; m < 4; ++m)
            #pragma unroll
            for (int n = 0; n < 4; ++n)
                acc[m][n] = __builtin_amdgcn_mfma_f32_16x16x32_bf16(
                    a[m], b[n], acc[m][n], 0, 0, 0);

        BAR_LGKM();   // reads of buf[cur] drained; kt+2 may overwrite it
    }

    // ---- extended K-tile (aliased into sA[0]/sA[1], dead after the loop):
    //   sAe[row(256)] = [xsq, 1, 0 x30]   sBe[row(128)] = [1, msq, 0 x30]
    ushort* sAe = &sA[0][0];     // 256*32 ushorts = 16 KB (exact)
    ushort* sBe = &sA[1][0];     // 128*32 ushorts =  8 KB
    {
        // all 4 uk-threads of a row obtain the full row sum
        float s0 = asq[0], s1 = asq[1], sb = bsq;
        s0 += __shfl_xor(s0, 1); s0 += __shfl_xor(s0, 2);
        s1 += __shfl_xor(s1, 1); s1 += __shfl_xor(s1, 2);
        sb += __shfl_xor(sb, 1); sb += __shfl_xor(sb, 2);
        #pragma unroll
        for (int i = 0; i < 2; ++i) {
            const int row = sr + i * 64 + upair * 128;
            uint4 w = {0u, 0u, 0u, 0u};
            if (uk == 0)
                w.x = (uint32_t)f2bfu(i ? s1 : s0) | (0x3F80u << 16); // [xsq,1]
            *(uint4*)(sAe + row * 32 + uk * 8) = w;
        }
        {
            const int row = sr + upair * 64;
            uint4 w = {0u, 0u, 0u, 0u};
            if (uk == 0)
                w.x = 0x3F80u | ((uint32_t)f2bfu(sb) << 16);          // [1,msq]
            *(uint4*)(sBe + row * 32 + uk * 8) = w;
        }
    }
    BAR_LGKM();

    {   // extra MFMA: adds xsq[r] + msq[o] into every accumulator element
        bf16x8 a[4], b[4];
        #pragma unroll
        for (int m = 0; m < 4; ++m)
            a[m] = *(const bf16x8*)(sAe + (wr*64 + m*16 + cl) * 32 + hi * 8);
        #pragma unroll
        for (int n = 0; n < 4; ++n)
            b[n] = *(const bf16x8*)(sBe + (wc*64 + n*16 + cl) * 32 + hi * 8);
        #pragma unroll
        for (int m = 0; m < 4; ++m)
            #pragma unroll
            for (int n = 0; n < 4; ++n)
                acc[m][n] = __builtin_amdgcn_mfma_f32_16x16x32_bf16(
                    a[m], b[n], acc[m][n], 0, 0, 0);
    }

    // epilogue: C/D layout col = lane&15, row = (lane>>4)*4 + j
    #pragma unroll
    for (int m = 0; m < 4; ++m) {
        #pragma unroll
        for (int j = 0; j < 4; ++j) {
            const int grow = brow + wr*64 + m*16 + hi*4 + j;
            float* orow = out + (size_t)grow * O_ROWS + bcol + wc*64 + cl;
            #pragma unroll
            for (int n = 0; n < 4; ++n)
                orow[n * 16] = rsqrtf(acc[m][n][j]);
        }
    }
    #undef LOADK
    #undef STAGEK
}

extern "C" void kernel_launch(void* const* d_in, const int* in_sizes, int n_in,
                              void* d_out, int out_size, void* d_ws, size_t ws_size,
                              hipStream_t stream) {
    const float* x    = (const float*)d_in[0];
    const float* mean = (const float*)d_in[1];
    float* out = (float*)d_out;

    quadra_kernel<<<dim3((N_ROWS / 256) * (O_ROWS / 128)), 512, 0, stream>>>(
        x, mean, out);
}